// Round 2
// baseline (2599.986 us; speedup 1.0000x reference)
//
#include <hip/hip_runtime.h>
#include <stdint.h>
#include <math.h>

#define S_LEN 2048
#define HID   4096
#define NH    32
#define HD    128
#define KSEL  256

typedef unsigned short u16;
typedef unsigned long long u64;
typedef __attribute__((ext_vector_type(8))) short short8;
typedef __attribute__((ext_vector_type(4))) float floatx4;

__device__ __forceinline__ float bf2f(u16 u){ return __uint_as_float(((unsigned)u) << 16); }
__device__ __forceinline__ u16 f2bf(float f){
  unsigned u = __float_as_uint(f);
  u += 0x7fffu + ((u >> 16) & 1u);   // RTNE
  return (u16)(u >> 16);
}
// monotonic float -> unsigned key (larger float -> larger key)
__device__ __forceinline__ unsigned okey(float x){
  unsigned b = __float_as_uint(x);
  return (b & 0x80000000u) ? ~b : (b | 0x80000000u);
}
__device__ __forceinline__ float unokey(unsigned k){
  unsigned b = (k & 0x80000000u) ? (k & 0x7fffffffu) : ~k;
  return __uint_as_float(b);
}
__device__ __forceinline__ void async16(const void* g, void* l){
  __builtin_amdgcn_global_load_lds((const __attribute__((address_space(1))) unsigned int*)g,
                                   (__attribute__((address_space(3))) unsigned int*)l,
                                   16, 0, 0);
}

// ---------------- dtype detection ----------------
__global__ void detect_dtype(const u16* __restrict__ h, int* __restrict__ flag){
  int cnt = 0;
  for (int i = threadIdx.x; i < 256; i += 64) {
    float v = bf2f(h[2*i]);
    float a = fabsf(v);
    if (a >= 1e-12f && a <= 16.0f) cnt++;
  }
  #pragma unroll
  for (int o = 32; o; o >>= 1) cnt += __shfl_down(cnt, o);
  if (threadIdx.x == 0) *flag = (cnt >= 160) ? 1 : 0;
}

__global__ void sentinel_kernel(float* out){ out[0] = 12345.0f; }

// ---------------- convert to canonical bf16 ----------------
__global__ void to_bf16(const void* __restrict__ src, u16* __restrict__ dst,
                        int n8, const int* __restrict__ flag)
{
  int i = blockIdx.x * blockDim.x + threadIdx.x;
  if (i >= n8) return;
  if (*flag != 0) {
    ((uint4*)dst)[i] = ((const uint4*)src)[i];
  } else {
    const float4* s = (const float4*)src;
    float4 a = s[2*i], b = s[2*i+1];
    uint4 u;
    u.x = (unsigned)f2bf(a.x) | ((unsigned)f2bf(a.y) << 16);
    u.y = (unsigned)f2bf(a.z) | ((unsigned)f2bf(a.w) << 16);
    u.z = (unsigned)f2bf(b.x) | ((unsigned)f2bf(b.y) << 16);
    u.w = (unsigned)f2bf(b.z) | ((unsigned)f2bf(b.w) << 16);
    ((uint4*)dst)[i] = u;
  }
}

// ---------------- GEMM: C[M,N] = A[M,K] * B[N,K]^T (NT), bf16 in, fp32 acc ----
__global__ __launch_bounds__(256) void gemm_bt(const u16* __restrict__ A,
    const u16* __restrict__ B, void* __restrict__ C,
    int M, int N, int K, int out_mode, const int* __restrict__ flag)
{
  __shared__ u16 As[128*64];
  __shared__ u16 Bs[128*64];
  const int tid  = threadIdx.x;
  const int wave = tid >> 6;
  const int lane = tid & 63;
  const int quad = lane >> 4;
  const int l16  = lane & 15;
  const int wr = wave >> 1, wc = wave & 1;
  const int bm = blockIdx.y * 128;
  const int bn = blockIdx.x * 128;
  const int rsub = lane >> 3;
  const int csub = lane & 7;

  floatx4 acc[4][4];
  #pragma unroll
  for (int i = 0; i < 4; i++)
    #pragma unroll
    for (int j = 0; j < 4; j++)
      #pragma unroll
      for (int r = 0; r < 4; r++) acc[i][j][r] = 0.0f;

  for (int k0 = 0; k0 < K; k0 += 64) {
    #pragma unroll
    for (int i = 0; i < 4; i++) {
      const int s = wave*4 + i;
      const int r = s*8 + rsub;
      const int c = csub ^ (r & 7);
      const size_t goff = (size_t)r * K + (size_t)(k0 + c*8);
      async16(A + (size_t)bm * K + goff, &As[s*512]);
      async16(B + (size_t)bn * K + goff, &Bs[s*512]);
    }
    __syncthreads();
    #pragma unroll
    for (int ks = 0; ks < 2; ks++) {
      short8 fa[4], fb[4];
      #pragma unroll
      for (int mi = 0; mi < 4; mi++) {
        int m = wr*64 + mi*16 + l16;
        int phys = (ks*4 + quad) ^ (m & 7);
        fa[mi] = *(const short8*)&As[m*64 + phys*8];
      }
      #pragma unroll
      for (int ni = 0; ni < 4; ni++) {
        int n = wc*64 + ni*16 + l16;
        int phys = (ks*4 + quad) ^ (n & 7);
        fb[ni] = *(const short8*)&Bs[n*64 + phys*8];
      }
      #pragma unroll
      for (int mi = 0; mi < 4; mi++)
        #pragma unroll
        for (int ni = 0; ni < 4; ni++)
          acc[mi][ni] = __builtin_amdgcn_mfma_f32_16x16x32_bf16(fa[mi], fb[ni], acc[mi][ni], 0, 0, 0);
    }
    __syncthreads();
  }

  const bool outbf = (out_mode == 0) || (*flag != 0);
  #pragma unroll
  for (int mi = 0; mi < 4; mi++) {
    #pragma unroll
    for (int ni = 0; ni < 4; ni++) {
      #pragma unroll
      for (int r = 0; r < 4; r++) {
        int row = bm + wr*64 + mi*16 + quad*4 + r;
        int col = bn + wc*64 + ni*16 + l16;
        float v = acc[mi][ni][r];
        size_t idx = (size_t)row * N + col;
        if (outbf) ((u16*)C)[idx] = f2bf(v);
        else       ((float*)C)[idx] = v;
      }
    }
  }
}

// ---------------- RoPE in place; Q additionally scaled by 1/sqrt(HD) --------
__global__ void rope_kernel(u16* __restrict__ Q, u16* __restrict__ Kb,
                            const int* __restrict__ pos)
{
  int n = blockIdx.x * blockDim.x + threadIdx.x;  // S*NH*64
  if (n >= S_LEN * NH * 64) return;
  int s   = n >> 11;
  int rem = n & 2047;
  int h = rem >> 6;
  int j = rem & 63;
  float p = (float)pos[s];
  float inv = expf(-(float)j * 0.14391156831212787f);  // ln(10000)/64
  float arg = p * inv;
  float c = cosf(arg), sn = sinf(arg);
  const float SC = 0.08838834764831845f;  // 1/sqrt(128), folded into Q
  size_t base = (size_t)s * HID + (size_t)h * HD + j;
  float q1 = bf2f(Q[base]), q2 = bf2f(Q[base + 64]);
  Q[base]      = f2bf((q1 * c - q2 * sn) * SC);
  Q[base + 64] = f2bf((q2 * c + q1 * sn) * SC);
  float k1 = bf2f(Kb[base]), k2 = bf2f(Kb[base + 64]);
  Kb[base]      = f2bf(k1 * c - k2 * sn);
  Kb[base + 64] = f2bf(k2 * c + k1 * sn);
}

// ---------------- attention: one block per (head, 16-row q-tile) ------------
// 512 threads (8 waves). Scores live in REGISTERS (16 floatx4 per thread).
// Phase 1 is branch-free: every c[i] is written on every path (clamped tile
// index for out-of-range waves) so the array has a clean live range and the
// allocator keeps it in VGPRs instead of scratch.
// Phase 2 keeps a per-row 16-bit "still matches prefix" register mask so
// radix passes >=1 only touch boundary items instead of re-scanning all 64.
// Phase 3 uses ballot compaction: 1 atomicAdd + 1 atomicMax per 16-lane
// group instead of 16+16 same-address atomics.
// LDS (41,472 B): hist u32[16][256] | sel f32[16][256] (score->weight) |
//                 idx u16[16][256] | state 512B
#define ATTN_LDS (16384 + 16384 + 8192 + 512)
__global__ __launch_bounds__(512, 2) void attn_kernel(const u16* __restrict__ Q,
    const u16* __restrict__ Kb, const u16* __restrict__ V, u16* __restrict__ O)
{
  extern __shared__ char smem[];
  unsigned* hist  = (unsigned*)smem;                  // [16][256]
  float*    sel   = (float*)(smem + 16384);           // [16][256]
  u16*      idxl  = (u16*)(smem + 32768);             // [16][256]
  char*     stb   = smem + 40960;
  u64*      pref  = (u64*)stb;                        // [16]
  unsigned* rneedA= (unsigned*)(stb + 128);           // [16]
  unsigned* shA   = (unsigned*)(stb + 192);           // [16]
  unsigned* doneA = (unsigned*)(stb + 256);           // [16]
  unsigned* cntA  = (unsigned*)(stb + 320);           // [16]
  unsigned* umaxA = (unsigned*)(stb + 384);           // [16]
  unsigned* flagT = (unsigned*)(stb + 448);           // [1]

  const int tid  = threadIdx.x;
  const int wave = tid >> 6, lane = tid & 63;
  const int quad = lane >> 4, l16 = lane & 15;
  const int quad4 = quad * 4;
  const int qt   = (S_LEN/16 - 1) - blockIdx.x;   // heavy tiles first
  const int q0   = qt * 16;
  const int h    = blockIdx.y;
  const size_t hoff = (size_t)h * HD;
  const int ntile = qt + 1;

  // state init (LDS untouched by phase 1 otherwise)
  if (tid < 16) {
    pref[tid]  = 0ull;
    rneedA[tid]= KSEL;
    doneA[tid] = ((q0 + tid + 1) > KSEL) ? 0u : 1u;  // !dosel rows skip passes
    cntA[tid]  = 0u;
    umaxA[tid] = 0u;
    shA[tid]   = 0u;
  }
  if (tid == 0) flagT[0] = 0u;

  // ---- Phase 1: scores via MFMA, K streamed from global, acc in registers --
  // Branch-free: out-of-range tiles recompute tile 0 (L2-hot) and are ignored
  // by later phases.  Every c[i] is unconditionally defined.
  floatx4 c[16];
  {
    short8 afr[4];
    const u16* qrow = Q + (size_t)(q0 + l16) * HID + hoff;
    #pragma unroll
    for (int ks = 0; ks < 4; ks++)
      afr[ks] = *(const short8*)(qrow + ks*32 + quad*8);

    #pragma unroll
    for (int i = 0; i < 16; i++) {
      int jt = wave + 8*i;
      int jtc = (jt < ntile) ? jt : 0;
      const u16* krow = Kb + (size_t)(jtc*16 + l16) * HID + hoff;
      floatx4 acc = {0.f, 0.f, 0.f, 0.f};
      #pragma unroll
      for (int ks = 0; ks < 4; ks++) {
        short8 bfr = *(const short8*)(krow + ks*32 + quad*8);
        acc = __builtin_amdgcn_mfma_f32_16x16x32_bf16(afr[ks], bfr, acc, 0, 0, 0);
      }
      c[i] = acc;   // rows quad4..quad4+3, col j = jt*16 + l16
    }
  }
  __syncthreads();

  // ---- Phase 2: radix select over register scores ----
  const int srow = tid >> 5;       // row owned by this half-wave for scans
  const int t    = tid & 31;

  unsigned bmask[4];               // bit i: item (i,r) may still match prefix

  for (int p = 0; p < 6; p++) {
    const int sh = 40 - 8*p;
    if (p >= 4 && flagT[0] == 0u) break;   // uniform: no boundary ties anywhere
    // zero histograms
    #pragma unroll
    for (int b = 0; b < 8; b++) hist[tid + b*512] = 0u;
    __syncthreads();
    // accumulate
    {
      unsigned myDone[4]; u64 myPref[4];
      #pragma unroll
      for (int r = 0; r < 4; r++) { myDone[r] = doneA[quad4+r]; myPref[r] = pref[quad4+r]; }
      if (p == 0) {
        #pragma unroll
        for (int r = 0; r < 4; r++) bmask[r] = 0u;
        #pragma unroll
        for (int i = 0; i < 16; i++) {
          int jt = wave + 8*i;
          if (jt < ntile) {
            int j = jt*16 + l16;
            #pragma unroll
            for (int r = 0; r < 4; r++) {
              int row = quad4 + r;
              if (j > q0 + row) continue;
              bmask[r] |= (1u << i);
              if (myDone[r]) continue;
              unsigned dig = okey(c[i][r]) >> 24;   // top 8 bits of 48-bit key
              atomicAdd(&hist[row*256 + dig], 1u);
            }
          }
        }
      } else {
        #pragma unroll
        for (int i = 0; i < 16; i++) {
          #pragma unroll
          for (int r = 0; r < 4; r++) {
            if (myDone[r]) continue;
            if (!(bmask[r] & (1u << i))) continue;
            int jt = wave + 8*i;
            int j = jt*16 + l16;
            int row = quad4 + r;
            u64 ek = ((u64)okey(c[i][r]) << 16) | (unsigned)((2047 - j) << 5);
            if ((ek >> (sh + 8)) == myPref[r])
              atomicAdd(&hist[row*256 + (unsigned)((ek >> sh) & 255u)], 1u);
            else
              bmask[r] &= ~(1u << i);
          }
        }
      }
    }
    __syncthreads();
    // digit scan: half-wave per row, 8 bins per lane, suffix order
    if (doneA[srow] == 0u) {
      unsigned hv[8], part = 0;
      const int baseb = srow*256 + 248 - 8*t;
      #pragma unroll
      for (int k2 = 0; k2 < 8; k2++) { hv[k2] = hist[baseb + k2]; part += hv[k2]; }
      unsigned pre = part;
      #pragma unroll
      for (int o = 1; o < 32; o <<= 1) { unsigned v2 = __shfl_up(pre, o, 32); if (t >= o) pre += v2; }
      pre -= part;   // count of keys in strictly higher chunks
      unsigned rn = rneedA[srow];
      if (pre < rn && pre + part >= rn) {     // unique finder lane
        unsigned a = pre;
        #pragma unroll
        for (int k2 = 7; k2 >= 0; k2--) {
          unsigned cc = hv[k2];
          if (a + cc >= rn) {
            unsigned dig = (unsigned)(248 - 8*t + k2);
            pref[srow] = (pref[srow] << 8) | dig;
            unsigned newr = rn - a;
            rneedA[srow] = newr;
            if (cc == newr) { doneA[srow] = 1u; shA[srow] = (unsigned)sh; }
            else if (sh == 16) flagT[0] = 1u;   // need index passes
            break;
          }
          a += cc;
        }
      }
    }
    __syncthreads();
  }

  // ---- Phase 3: compaction (exactly min(valid,KSEL) per row) + row max ----
  // Ballot-compacted: one atomicAdd / atomicMax per 16-lane row group.
  {
    u64 myT[4]; unsigned mySh[4]; bool myDs[4];
    #pragma unroll
    for (int r = 0; r < 4; r++) {
      int rr = quad4 + r;
      myT[r] = pref[rr]; mySh[r] = shA[rr];
      myDs[r] = (q0 + rr + 1) > KSEL;
    }
    #pragma unroll
    for (int i = 0; i < 16; i++) {
      int jt = wave + 8*i;
      if (jt < ntile) {                       // wave-uniform branch
        int j = jt*16 + l16;
        #pragma unroll
        for (int r = 0; r < 4; r++) {
          int row = quad4 + r;
          float s = c[i][r];
          bool keep = (j <= q0 + row);
          if (keep && myDs[r]) {
            u64 ek = ((u64)okey(s) << 16) | (unsigned)((2047 - j) << 5);
            keep = (ek >> mySh[r]) >= myT[r];
          }
          u64 bal = __ballot(keep);
          unsigned seg = (unsigned)((bal >> (quad*16)) & 0xffffull);
          if (seg) {                          // uniform within 16-lane group
            int leader = __ffs(seg) - 1;
            unsigned base = 0;
            if (l16 == leader) base = atomicAdd(&cntA[row], (unsigned)__popc(seg));
            base = __shfl(base, quad*16 + leader, 64);
            unsigned ok = keep ? okey(s) : 0u;
            #pragma unroll
            for (int o = 8; o; o >>= 1) {
              unsigned other = __shfl_xor(ok, o, 64);
              ok = ok > other ? ok : other;
            }
            if (l16 == leader) atomicMax(&umaxA[row], ok);
            if (keep) {
              unsigned pos = base + (unsigned)__popc(seg & ((1u << l16) - 1u));
              idxl[row*256 + pos] = (u16)j;
              sel[row*256 + pos]  = s;
            }
          }
        }
      }
    }
  }
  __syncthreads();

  // ---- Phase 4: softmax weights per row (half-wave) ----
  const int n = (int)cntA[srow];
  {
    const float m = unokey(umaxA[srow]);
    float lsum = 0.f;
    for (int i = t; i < n; i += 32) {
      float w = __expf(sel[srow*256 + i] - m);
      sel[srow*256 + i] = w;
      lsum += w;
    }
    #pragma unroll
    for (int o = 16; o; o >>= 1) lsum += __shfl_down(lsum, o, 32);
    lsum = __shfl(lsum, 0, 32);
    umaxA[srow] = __float_as_uint(1.f / lsum);  // stash invs (safe: umax dead)
  }
  __syncthreads();

  // ---- Phase 5: PV over compacted list; half-wave per row, 4 dims/lane ----
  {
    const float invs = __uint_as_float(umaxA[srow]);
    const int d0 = t * 4;
    float a0 = 0.f, a1 = 0.f, a2 = 0.f, a3 = 0.f;
    int i = 0;
    for (; i + 4 <= n; i += 4) {
      int   j0 = idxl[srow*256+i+0], j1 = idxl[srow*256+i+1],
            j2 = idxl[srow*256+i+2], j3 = idxl[srow*256+i+3];
      float w0 = sel[srow*256+i+0], w1 = sel[srow*256+i+1],
            w2 = sel[srow*256+i+2], w3 = sel[srow*256+i+3];
      uint2 p0 = *(const uint2*)(V + (size_t)j0 * HID + hoff + d0);
      uint2 p1 = *(const uint2*)(V + (size_t)j1 * HID + hoff + d0);
      uint2 p2 = *(const uint2*)(V + (size_t)j2 * HID + hoff + d0);
      uint2 p3 = *(const uint2*)(V + (size_t)j3 * HID + hoff + d0);
      a0 += w0*__uint_as_float(p0.x<<16) + w1*__uint_as_float(p1.x<<16)
          + w2*__uint_as_float(p2.x<<16) + w3*__uint_as_float(p3.x<<16);
      a1 += w0*__uint_as_float(p0.x&0xffff0000u) + w1*__uint_as_float(p1.x&0xffff0000u)
          + w2*__uint_as_float(p2.x&0xffff0000u) + w3*__uint_as_float(p3.x&0xffff0000u);
      a2 += w0*__uint_as_float(p0.y<<16) + w1*__uint_as_float(p1.y<<16)
          + w2*__uint_as_float(p2.y<<16) + w3*__uint_as_float(p3.y<<16);
      a3 += w0*__uint_as_float(p0.y&0xffff0000u) + w1*__uint_as_float(p1.y&0xffff0000u)
          + w2*__uint_as_float(p2.y&0xffff0000u) + w3*__uint_as_float(p3.y&0xffff0000u);
    }
    for (; i < n; i++) {
      int j = idxl[srow*256+i]; float w = sel[srow*256+i];
      uint2 p = *(const uint2*)(V + (size_t)j * HID + hoff + d0);
      a0 += w*__uint_as_float(p.x<<16);  a1 += w*__uint_as_float(p.x&0xffff0000u);
      a2 += w*__uint_as_float(p.y<<16);  a3 += w*__uint_as_float(p.y&0xffff0000u);
    }
    uint2 ov;
    ov.x = (unsigned)f2bf(a0*invs) | ((unsigned)f2bf(a1*invs) << 16);
    ov.y = (unsigned)f2bf(a2*invs) | ((unsigned)f2bf(a3*invs) << 16);
    *(uint2*)(O + (size_t)(q0 + srow) * HID + hoff + d0) = ov;
  }
}

// ---------------- launch ----------------
extern "C" void kernel_launch(void* const* d_in, const int* in_sizes, int n_in,
                              void* d_out, int out_size, void* d_ws, size_t ws_size,
                              hipStream_t stream)
{
  (void)in_sizes; (void)n_in; (void)out_size;
  const void* hidden = d_in[0];
  const int*  pos    = (const int*)d_in[2];
  const void* Wq     = d_in[3];
  const void* Wk     = d_in[4];
  const void* Wv     = d_in[5];
  const void* Wo     = d_in[6];

  const size_t SH2 = (size_t)S_LEN * HID * 2;
  const size_t W2  = (size_t)HID * HID * 2;
  const size_t NEEDED = 256 + SH2 + W2 + 3 * SH2 + SH2;
  if (ws_size < NEEDED) {
    sentinel_kernel<<<1, 1, 0, stream>>>((float*)d_out);
    return;
  }

  char* ws = (char*)d_ws;
  int* flag = (int*)ws;
  u16* hb = (u16*)(ws + 256);
  u16* wb = (u16*)(ws + 256 + SH2);
  u16* qb = (u16*)(ws + 256 + SH2 + W2);
  u16* kb = (u16*)(ws + 256 + SH2 + W2 + SH2);
  u16* vb = (u16*)(ws + 256 + SH2 + W2 + 2 * SH2);
  u16* ab = (u16*)(ws + 256 + SH2 + W2 + 3 * SH2);

  detect_dtype<<<1, 64, 0, stream>>>((const u16*)hidden, flag);

  const int nh8 = S_LEN * HID / 8;
  const int nw8 = HID * HID / 8;
  to_bf16<<<nh8 / 256, 256, 0, stream>>>(hidden, hb, nh8, flag);

  dim3 ggrid(HID / 128, S_LEN / 128);

  to_bf16<<<nw8 / 256, 256, 0, stream>>>(Wq, wb, nw8, flag);
  gemm_bt<<<ggrid, 256, 0, stream>>>(hb, wb, (void*)qb, S_LEN, HID, HID, 0, flag);

  to_bf16<<<nw8 / 256, 256, 0, stream>>>(Wk, wb, nw8, flag);
  gemm_bt<<<ggrid, 256, 0, stream>>>(hb, wb, (void*)kb, S_LEN, HID, HID, 0, flag);

  to_bf16<<<nw8 / 256, 256, 0, stream>>>(Wv, wb, nw8, flag);
  gemm_bt<<<ggrid, 256, 0, stream>>>(hb, wb, (void*)vb, S_LEN, HID, HID, 0, flag);

  rope_kernel<<<(S_LEN * NH * 64) / 256, 256, 0, stream>>>(qb, kb, pos);

  attn_kernel<<<dim3(S_LEN / 16, NH), 512, ATTN_LDS, stream>>>(qb, kb, vb, ab);

  to_bf16<<<nw8 / 256, 256, 0, stream>>>(Wo, wb, nw8, flag);
  gemm_bt<<<ggrid, 256, 0, stream>>>(ab, wb, d_out, S_LEN, HID, HID, 1, flag);
}

// Round 3
// 1762.956 us; speedup vs baseline: 1.4748x; 1.4748x over previous
//
#include <hip/hip_runtime.h>
#include <stdint.h>
#include <math.h>

#define S_LEN 2048
#define HID   4096
#define NH    32
#define HD    128
#define KSEL  256

typedef unsigned short u16;
typedef unsigned long long u64;
typedef __attribute__((ext_vector_type(8))) short short8;
typedef __attribute__((ext_vector_type(4))) float floatx4;

__device__ __forceinline__ float bf2f(u16 u){ return __uint_as_float(((unsigned)u) << 16); }
__device__ __forceinline__ u16 f2bf(float f){
  unsigned u = __float_as_uint(f);
  u += 0x7fffu + ((u >> 16) & 1u);   // RTNE
  return (u16)(u >> 16);
}
// monotonic float -> unsigned key (larger float -> larger key)
__device__ __forceinline__ unsigned okey(float x){
  unsigned b = __float_as_uint(x);
  return (b & 0x80000000u) ? ~b : (b | 0x80000000u);
}
__device__ __forceinline__ float unokey(unsigned k){
  unsigned b = (k & 0x80000000u) ? (k & 0x7fffffffu) : ~k;
  return __uint_as_float(b);
}
__device__ __forceinline__ void async16(const void* g, void* l){
  __builtin_amdgcn_global_load_lds((const __attribute__((address_space(1))) unsigned int*)g,
                                   (__attribute__((address_space(3))) unsigned int*)l,
                                   16, 0, 0);
}

// ---------------- dtype detection ----------------
__global__ void detect_dtype(const u16* __restrict__ h, int* __restrict__ flag){
  int cnt = 0;
  for (int i = threadIdx.x; i < 256; i += 64) {
    float v = bf2f(h[2*i]);
    float a = fabsf(v);
    if (a >= 1e-12f && a <= 16.0f) cnt++;
  }
  #pragma unroll
  for (int o = 32; o; o >>= 1) cnt += __shfl_down(cnt, o);
  if (threadIdx.x == 0) *flag = (cnt >= 160) ? 1 : 0;
}

__global__ void sentinel_kernel(float* out){ out[0] = 12345.0f; }

// ---------------- convert to canonical bf16 ----------------
__global__ void to_bf16(const void* __restrict__ src, u16* __restrict__ dst,
                        int n8, const int* __restrict__ flag)
{
  int i = blockIdx.x * blockDim.x + threadIdx.x;
  if (i >= n8) return;
  if (*flag != 0) {
    ((uint4*)dst)[i] = ((const uint4*)src)[i];
  } else {
    const float4* s = (const float4*)src;
    float4 a = s[2*i], b = s[2*i+1];
    uint4 u;
    u.x = (unsigned)f2bf(a.x) | ((unsigned)f2bf(a.y) << 16);
    u.y = (unsigned)f2bf(a.z) | ((unsigned)f2bf(a.w) << 16);
    u.z = (unsigned)f2bf(b.x) | ((unsigned)f2bf(b.y) << 16);
    u.w = (unsigned)f2bf(b.z) | ((unsigned)f2bf(b.w) << 16);
    ((uint4*)dst)[i] = u;
  }
}

// ---------------- GEMM: C[M,N] = A[M,K] * B[N,K]^T (NT), bf16 in, fp32 acc ----
__global__ __launch_bounds__(256) void gemm_bt(const u16* __restrict__ A,
    const u16* __restrict__ B, void* __restrict__ C,
    int M, int N, int K, int out_mode, const int* __restrict__ flag)
{
  __shared__ u16 As[128*64];
  __shared__ u16 Bs[128*64];
  const int tid  = threadIdx.x;
  const int wave = tid >> 6;
  const int lane = tid & 63;
  const int quad = lane >> 4;
  const int l16  = lane & 15;
  const int wr = wave >> 1, wc = wave & 1;
  const int bm = blockIdx.y * 128;
  const int bn = blockIdx.x * 128;
  const int rsub = lane >> 3;
  const int csub = lane & 7;

  floatx4 acc[4][4];
  #pragma unroll
  for (int i = 0; i < 4; i++)
    #pragma unroll
    for (int j = 0; j < 4; j++)
      #pragma unroll
      for (int r = 0; r < 4; r++) acc[i][j][r] = 0.0f;

  for (int k0 = 0; k0 < K; k0 += 64) {
    #pragma unroll
    for (int i = 0; i < 4; i++) {
      const int s = wave*4 + i;
      const int r = s*8 + rsub;
      const int c = csub ^ (r & 7);
      const size_t goff = (size_t)r * K + (size_t)(k0 + c*8);
      async16(A + (size_t)bm * K + goff, &As[s*512]);
      async16(B + (size_t)bn * K + goff, &Bs[s*512]);
    }
    __syncthreads();
    #pragma unroll
    for (int ks = 0; ks < 2; ks++) {
      short8 fa[4], fb[4];
      #pragma unroll
      for (int mi = 0; mi < 4; mi++) {
        int m = wr*64 + mi*16 + l16;
        int phys = (ks*4 + quad) ^ (m & 7);
        fa[mi] = *(const short8*)&As[m*64 + phys*8];
      }
      #pragma unroll
      for (int ni = 0; ni < 4; ni++) {
        int n = wc*64 + ni*16 + l16;
        int phys = (ks*4 + quad) ^ (n & 7);
        fb[ni] = *(const short8*)&Bs[n*64 + phys*8];
      }
      #pragma unroll
      for (int mi = 0; mi < 4; mi++)
        #pragma unroll
        for (int ni = 0; ni < 4; ni++)
          acc[mi][ni] = __builtin_amdgcn_mfma_f32_16x16x32_bf16(fa[mi], fb[ni], acc[mi][ni], 0, 0, 0);
    }
    __syncthreads();
  }

  const bool outbf = (out_mode == 0) || (*flag != 0);
  #pragma unroll
  for (int mi = 0; mi < 4; mi++) {
    #pragma unroll
    for (int ni = 0; ni < 4; ni++) {
      #pragma unroll
      for (int r = 0; r < 4; r++) {
        int row = bm + wr*64 + mi*16 + quad*4 + r;
        int col = bn + wc*64 + ni*16 + l16;
        float v = acc[mi][ni][r];
        size_t idx = (size_t)row * N + col;
        if (outbf) ((u16*)C)[idx] = f2bf(v);
        else       ((float*)C)[idx] = v;
      }
    }
  }
}

// ---------------- RoPE in place; Q additionally scaled by 1/sqrt(HD) --------
__global__ void rope_kernel(u16* __restrict__ Q, u16* __restrict__ Kb,
                            const int* __restrict__ pos)
{
  int n = blockIdx.x * blockDim.x + threadIdx.x;  // S*NH*64
  if (n >= S_LEN * NH * 64) return;
  int s   = n >> 11;
  int rem = n & 2047;
  int h = rem >> 6;
  int j = rem & 63;
  float p = (float)pos[s];
  float inv = expf(-(float)j * 0.14391156831212787f);  // ln(10000)/64
  float arg = p * inv;
  float c = cosf(arg), sn = sinf(arg);
  const float SC = 0.08838834764831845f;  // 1/sqrt(128), folded into Q
  size_t base = (size_t)s * HID + (size_t)h * HD + j;
  float q1 = bf2f(Q[base]), q2 = bf2f(Q[base + 64]);
  Q[base]      = f2bf((q1 * c - q2 * sn) * SC);
  Q[base + 64] = f2bf((q2 * c + q1 * sn) * SC);
  float k1 = bf2f(Kb[base]), k2 = bf2f(Kb[base + 64]);
  Kb[base]      = f2bf(k1 * c - k2 * sn);
  Kb[base + 64] = f2bf(k2 * c + k1 * sn);
}

// ---------------- attention: one block per (head, 16-row q-tile) ------------
// 1024 threads (16 waves).  Wave w computes K-tiles {w, w+16, ...} -> only
// 8 tile-slots per thread; score keys live in 32 u32 VGPRs (okey form).
// 16-wave blocks require VGPR <= 128 (4 waves/SIMD) to launch; peak live
// here is ~100 regs, so no scratch spill (R1/R2 spilled 1-3 GB with the
// 512-thread/64-score layout).
// Radix passes 0-3 compare in pure 32-bit okey; rare index-tiebreak passes
// 4-5 use the 48-bit composite key.  Boundary bmask restricts passes >=1
// to still-matching items.  Ballot compaction: 1 atomic per 16-lane group.
// LDS (41,472 B): hist u32[16][256] | sel f32[16][256] | idx u16[16][256] |
//                 state 512B
#define ATTN_LDS (16384 + 16384 + 8192 + 512)
__global__ __launch_bounds__(1024, 1) void attn_kernel(const u16* __restrict__ Q,
    const u16* __restrict__ Kb, const u16* __restrict__ V, u16* __restrict__ O)
{
  extern __shared__ char smem[];
  unsigned* hist  = (unsigned*)smem;                  // [16][256]
  float*    sel   = (float*)(smem + 16384);           // [16][256]
  u16*      idxl  = (u16*)(smem + 32768);             // [16][256]
  char*     stb   = smem + 40960;
  u64*      pref  = (u64*)stb;                        // [16]
  unsigned* rneedA= (unsigned*)(stb + 128);           // [16]
  unsigned* shA   = (unsigned*)(stb + 192);           // [16]
  unsigned* doneA = (unsigned*)(stb + 256);           // [16]
  unsigned* cntA  = (unsigned*)(stb + 320);           // [16]
  unsigned* umaxA = (unsigned*)(stb + 384);           // [16]
  unsigned* flagT = (unsigned*)(stb + 448);           // [1]

  const int tid  = threadIdx.x;
  const int wave = tid >> 6, lane = tid & 63;
  const int quad = lane >> 4, l16 = lane & 15;
  const int quad4 = quad * 4;
  const int qt   = (S_LEN/16 - 1) - blockIdx.x;   // heavy tiles first
  const int q0   = qt * 16;
  const int h    = blockIdx.y;
  const size_t hoff = (size_t)h * HD;
  const int ntile = qt + 1;

  // state init
  if (tid < 16) {
    pref[tid]  = 0ull;
    rneedA[tid]= KSEL;
    doneA[tid] = ((q0 + tid + 1) > KSEL) ? 0u : 1u;  // !dosel rows skip passes
    cntA[tid]  = 0u;
    umaxA[tid] = 0u;
    shA[tid]   = 0u;
  }
  if (tid == 0) flagT[0] = 0u;

  // ---- Phase 1: scores via MFMA, K streamed from global; okey in registers --
  unsigned ko[8][4];   // [tile-slot][row-in-quad] -> monotonic u32 key
  {
    short8 afr[4];
    const u16* qrow = Q + (size_t)(q0 + l16) * HID + hoff;
    #pragma unroll
    for (int ks = 0; ks < 4; ks++)
      afr[ks] = *(const short8*)(qrow + ks*32 + quad*8);

    #pragma unroll
    for (int i = 0; i < 8; i++) {
      int jt = wave + 16*i;
      if (jt < ntile) {
        const u16* krow = Kb + (size_t)(jt*16 + l16) * HID + hoff;
        floatx4 acc = {0.f, 0.f, 0.f, 0.f};
        #pragma unroll
        for (int ks = 0; ks < 4; ks++) {
          short8 bfr = *(const short8*)(krow + ks*32 + quad*8);
          acc = __builtin_amdgcn_mfma_f32_16x16x32_bf16(afr[ks], bfr, acc, 0, 0, 0);
        }
        #pragma unroll
        for (int r = 0; r < 4; r++) ko[i][r] = okey(acc[r]);
      } else {
        #pragma unroll
        for (int r = 0; r < 4; r++) ko[i][r] = 0u;
      }
    }
  }
  __syncthreads();

  // ---- Phase 2: radix select (keys in registers, 32-bit fast path) ----
  const int srow = tid >> 6;       // wave per row for digit scans
  const int t64  = lane;

  unsigned bmask[4];               // bit i: item (i,r) may still match prefix

  for (int p = 0; p < 6; p++) {
    if (p >= 4 && flagT[0] == 0u) break;   // no boundary ties anywhere
    // zero histograms (prev pass's scan completed before last barrier)
    #pragma unroll
    for (int b = 0; b < 4; b++) hist[tid + b*1024] = 0u;
    __syncthreads();
    // accumulate
    {
      unsigned myDone[4];
      #pragma unroll
      for (int r = 0; r < 4; r++) myDone[r] = doneA[quad4+r];
      if (p == 0) {
        #pragma unroll
        for (int r = 0; r < 4; r++) bmask[r] = 0u;
        #pragma unroll
        for (int i = 0; i < 8; i++) {
          int jt = wave + 16*i;
          if (jt < ntile) {
            int j = jt*16 + l16;
            #pragma unroll
            for (int r = 0; r < 4; r++) {
              int row = quad4 + r;
              if (j > q0 + row) continue;
              bmask[r] |= (1u << i);
              if (myDone[r]) continue;
              atomicAdd(&hist[row*256 + (ko[i][r] >> 24)], 1u);
            }
          }
        }
      } else if (p < 4) {
        unsigned myPref[4];
        #pragma unroll
        for (int r = 0; r < 4; r++) myPref[r] = (unsigned)pref[quad4+r];
        const int sh32 = 32 - 8*p;           // prefix compare shift
        #pragma unroll
        for (int i = 0; i < 8; i++) {
          #pragma unroll
          for (int r = 0; r < 4; r++) {
            if (myDone[r]) continue;
            if (!(bmask[r] & (1u << i))) continue;
            unsigned ok = ko[i][r];
            if ((ok >> sh32) == myPref[r])
              atomicAdd(&hist[(quad4+r)*256 + ((ok >> (sh32 - 8)) & 255u)], 1u);
            else
              bmask[r] &= ~(1u << i);
          }
        }
      } else {
        // index-tiebreak passes (rare): 48-bit composite key
        u64 myPref[4];
        #pragma unroll
        for (int r = 0; r < 4; r++) myPref[r] = pref[quad4+r];
        const int sh = 40 - 8*p;             // 8 or 0
        #pragma unroll
        for (int i = 0; i < 8; i++) {
          #pragma unroll
          for (int r = 0; r < 4; r++) {
            if (myDone[r]) continue;
            if (!(bmask[r] & (1u << i))) continue;
            int jt = wave + 16*i;
            int j = jt*16 + l16;
            u64 ek = ((u64)ko[i][r] << 16) | (unsigned)((2047 - j) << 5);
            if ((ek >> (sh + 8)) == myPref[r])
              atomicAdd(&hist[(quad4+r)*256 + (unsigned)((ek >> sh) & 255u)], 1u);
            else
              bmask[r] &= ~(1u << i);
          }
        }
      }
    }
    __syncthreads();
    // digit scan: wave per row, 4 bins per lane, suffix (descending) order
    if (doneA[srow] == 0u) {
      unsigned hv[4], part = 0;
      const int baseb = srow*256 + 252 - 4*t64;
      #pragma unroll
      for (int k2 = 0; k2 < 4; k2++) { hv[k2] = hist[baseb + k2]; part += hv[k2]; }
      unsigned pre = part;
      #pragma unroll
      for (int o = 1; o < 64; o <<= 1) { unsigned v2 = __shfl_up(pre, o, 64); if (t64 >= o) pre += v2; }
      pre -= part;   // count of keys in strictly higher chunks
      unsigned rn = rneedA[srow];
      if (pre < rn && pre + part >= rn) {     // unique finder lane
        unsigned a = pre;
        #pragma unroll
        for (int k2 = 3; k2 >= 0; k2--) {
          unsigned cc = hv[k2];
          if (a + cc >= rn) {
            unsigned dig = (unsigned)(252 - 4*t64 + k2);
            pref[srow] = (pref[srow] << 8) | dig;
            unsigned newr = rn - a;
            rneedA[srow] = newr;
            if (cc == newr) { doneA[srow] = 1u; shA[srow] = (unsigned)(40 - 8*p); }
            else if (p == 3) flagT[0] = 1u;   // need index passes
            break;
          }
          a += cc;
        }
      }
    }
    __syncthreads();
  }

  // ---- Phase 3: ballot compaction (exactly min(valid,KSEL) per row) -------
  {
    u64 myT[4]; unsigned mySh[4]; bool myDs[4];
    #pragma unroll
    for (int r = 0; r < 4; r++) {
      int rr = quad4 + r;
      myT[r] = pref[rr]; mySh[r] = shA[rr];
      myDs[r] = (q0 + rr + 1) > KSEL;
    }
    #pragma unroll
    for (int i = 0; i < 8; i++) {
      int jt = wave + 16*i;
      if (jt < ntile) {                       // wave-uniform branch
        int j = jt*16 + l16;
        #pragma unroll
        for (int r = 0; r < 4; r++) {
          int row = quad4 + r;
          unsigned ok = ko[i][r];
          bool keep = (j <= q0 + row);
          if (keep && myDs[r]) {
            u64 ek = ((u64)ok << 16) | (unsigned)((2047 - j) << 5);
            keep = (ek >> mySh[r]) >= myT[r];
          }
          u64 bal = __ballot(keep);
          unsigned seg = (unsigned)((bal >> (quad*16)) & 0xffffull);
          if (seg) {                          // uniform within 16-lane group
            int leader = __ffs(seg) - 1;
            unsigned base = 0;
            if (l16 == leader) base = atomicAdd(&cntA[row], (unsigned)__popc(seg));
            base = __shfl(base, quad*16 + leader, 64);
            unsigned km = keep ? ok : 0u;
            #pragma unroll
            for (int o = 8; o; o >>= 1) {
              unsigned other = __shfl_xor(km, o, 64);
              km = km > other ? km : other;
            }
            if (l16 == leader) atomicMax(&umaxA[row], km);
            if (keep) {
              unsigned pos = base + (unsigned)__popc(seg & ((1u << l16) - 1u));
              idxl[row*256 + pos] = (u16)j;
              sel[row*256 + pos]  = unokey(ok);
            }
          }
        }
      }
    }
  }
  __syncthreads();

  // ---- Phase 4: softmax weights per row (full wave per row) ----
  const int n = (int)cntA[srow];
  {
    const float m = unokey(umaxA[srow]);
    float lsum = 0.f;
    for (int i = t64; i < n; i += 64) {
      float w = __expf(sel[srow*256 + i] - m);
      sel[srow*256 + i] = w;
      lsum += w;
    }
    #pragma unroll
    for (int o = 32; o; o >>= 1) lsum += __shfl_down(lsum, o, 64);
    lsum = __shfl(lsum, 0, 64);
    umaxA[srow] = __float_as_uint(1.f / lsum);  // stash invs (umax dead)
  }
  __syncthreads();

  // ---- Phase 5: PV over compacted list; wave per row, 2 dims/lane ----
  {
    const float invs = __uint_as_float(umaxA[srow]);
    const int d0 = t64 * 2;
    float a0 = 0.f, a1 = 0.f;
    int i = 0;
    for (; i + 4 <= n; i += 4) {
      int   j0 = idxl[srow*256+i+0], j1 = idxl[srow*256+i+1],
            j2 = idxl[srow*256+i+2], j3 = idxl[srow*256+i+3];
      float w0 = sel[srow*256+i+0], w1 = sel[srow*256+i+1],
            w2 = sel[srow*256+i+2], w3 = sel[srow*256+i+3];
      unsigned p0 = *(const unsigned*)(V + (size_t)j0 * HID + hoff + d0);
      unsigned p1 = *(const unsigned*)(V + (size_t)j1 * HID + hoff + d0);
      unsigned p2 = *(const unsigned*)(V + (size_t)j2 * HID + hoff + d0);
      unsigned p3 = *(const unsigned*)(V + (size_t)j3 * HID + hoff + d0);
      a0 += w0*__uint_as_float(p0<<16) + w1*__uint_as_float(p1<<16)
          + w2*__uint_as_float(p2<<16) + w3*__uint_as_float(p3<<16);
      a1 += w0*__uint_as_float(p0&0xffff0000u) + w1*__uint_as_float(p1&0xffff0000u)
          + w2*__uint_as_float(p2&0xffff0000u) + w3*__uint_as_float(p3&0xffff0000u);
    }
    for (; i < n; i++) {
      int j = idxl[srow*256+i]; float w = sel[srow*256+i];
      unsigned p = *(const unsigned*)(V + (size_t)j * HID + hoff + d0);
      a0 += w*__uint_as_float(p<<16);
      a1 += w*__uint_as_float(p&0xffff0000u);
    }
    unsigned ov = (unsigned)f2bf(a0*invs) | ((unsigned)f2bf(a1*invs) << 16);
    *(unsigned*)(O + (size_t)(q0 + srow) * HID + hoff + d0) = ov;
  }
}

// ---------------- launch ----------------
extern "C" void kernel_launch(void* const* d_in, const int* in_sizes, int n_in,
                              void* d_out, int out_size, void* d_ws, size_t ws_size,
                              hipStream_t stream)
{
  (void)in_sizes; (void)n_in; (void)out_size;
  const void* hidden = d_in[0];
  const int*  pos    = (const int*)d_in[2];
  const void* Wq     = d_in[3];
  const void* Wk     = d_in[4];
  const void* Wv     = d_in[5];
  const void* Wo     = d_in[6];

  const size_t SH2 = (size_t)S_LEN * HID * 2;
  const size_t W2  = (size_t)HID * HID * 2;
  const size_t NEEDED = 256 + SH2 + W2 + 3 * SH2 + SH2;
  if (ws_size < NEEDED) {
    sentinel_kernel<<<1, 1, 0, stream>>>((float*)d_out);
    return;
  }

  char* ws = (char*)d_ws;
  int* flag = (int*)ws;
  u16* hb = (u16*)(ws + 256);
  u16* wb = (u16*)(ws + 256 + SH2);
  u16* qb = (u16*)(ws + 256 + SH2 + W2);
  u16* kb = (u16*)(ws + 256 + SH2 + W2 + SH2);
  u16* vb = (u16*)(ws + 256 + SH2 + W2 + 2 * SH2);
  u16* ab = (u16*)(ws + 256 + SH2 + W2 + 3 * SH2);

  detect_dtype<<<1, 64, 0, stream>>>((const u16*)hidden, flag);

  const int nh8 = S_LEN * HID / 8;
  const int nw8 = HID * HID / 8;
  to_bf16<<<nh8 / 256, 256, 0, stream>>>(hidden, hb, nh8, flag);

  dim3 ggrid(HID / 128, S_LEN / 128);

  to_bf16<<<nw8 / 256, 256, 0, stream>>>(Wq, wb, nw8, flag);
  gemm_bt<<<ggrid, 256, 0, stream>>>(hb, wb, (void*)qb, S_LEN, HID, HID, 0, flag);

  to_bf16<<<nw8 / 256, 256, 0, stream>>>(Wk, wb, nw8, flag);
  gemm_bt<<<ggrid, 256, 0, stream>>>(hb, wb, (void*)kb, S_LEN, HID, HID, 0, flag);

  to_bf16<<<nw8 / 256, 256, 0, stream>>>(Wv, wb, nw8, flag);
  gemm_bt<<<ggrid, 256, 0, stream>>>(hb, wb, (void*)vb, S_LEN, HID, HID, 0, flag);

  rope_kernel<<<(S_LEN * NH * 64) / 256, 256, 0, stream>>>(qb, kb, pos);

  attn_kernel<<<dim3(S_LEN / 16, NH), 1024, ATTN_LDS, stream>>>(qb, kb, vb, ab);

  to_bf16<<<nw8 / 256, 256, 0, stream>>>(Wo, wb, nw8, flag);
  gemm_bt<<<ggrid, 256, 0, stream>>>(ab, wb, d_out, S_LEN, HID, HID, 1, flag);
}

// Round 4
// 1327.644 us; speedup vs baseline: 1.9583x; 1.3279x over previous
//
#include <hip/hip_runtime.h>
#include <stdint.h>
#include <math.h>

#define S_LEN 2048
#define HID   4096
#define NH    32
#define HD    128
#define KSEL  256

typedef unsigned short u16;
typedef unsigned long long u64;
typedef __attribute__((ext_vector_type(8))) short short8;
typedef __attribute__((ext_vector_type(4))) float floatx4;

__device__ __forceinline__ float bf2f(u16 u){ return __uint_as_float(((unsigned)u) << 16); }
__device__ __forceinline__ u16 f2bf(float f){
  unsigned u = __float_as_uint(f);
  u += 0x7fffu + ((u >> 16) & 1u);   // RTNE
  return (u16)(u >> 16);
}
// monotonic float -> unsigned key (larger float -> larger key); exact bijection
__device__ __forceinline__ unsigned okey(float x){
  unsigned b = __float_as_uint(x);
  return (b & 0x80000000u) ? ~b : (b | 0x80000000u);
}
__device__ __forceinline__ float unokey(unsigned k){
  unsigned b = (k & 0x80000000u) ? (k & 0x7fffffffu) : ~k;
  return __uint_as_float(b);
}
__device__ __forceinline__ void async16(const void* g, void* l){
  __builtin_amdgcn_global_load_lds((const __attribute__((address_space(1))) unsigned int*)g,
                                   (__attribute__((address_space(3))) unsigned int*)l,
                                   16, 0, 0);
}

// ---------------- dtype detection ----------------
__global__ void detect_dtype(const u16* __restrict__ h, int* __restrict__ flag){
  int cnt = 0;
  for (int i = threadIdx.x; i < 256; i += 64) {
    float v = bf2f(h[2*i]);
    float a = fabsf(v);
    if (a >= 1e-12f && a <= 16.0f) cnt++;
  }
  #pragma unroll
  for (int o = 32; o; o >>= 1) cnt += __shfl_down(cnt, o);
  if (threadIdx.x == 0) *flag = (cnt >= 160) ? 1 : 0;
}

__global__ void sentinel_kernel(float* out){ out[0] = 12345.0f; }

// ---------------- convert to canonical bf16 ----------------
__global__ void to_bf16(const void* __restrict__ src, u16* __restrict__ dst,
                        int n8, const int* __restrict__ flag)
{
  int i = blockIdx.x * blockDim.x + threadIdx.x;
  if (i >= n8) return;
  if (*flag != 0) {
    ((uint4*)dst)[i] = ((const uint4*)src)[i];
  } else {
    const float4* s = (const float4*)src;
    float4 a = s[2*i], b = s[2*i+1];
    uint4 u;
    u.x = (unsigned)f2bf(a.x) | ((unsigned)f2bf(a.y) << 16);
    u.y = (unsigned)f2bf(a.z) | ((unsigned)f2bf(a.w) << 16);
    u.z = (unsigned)f2bf(b.x) | ((unsigned)f2bf(b.y) << 16);
    u.w = (unsigned)f2bf(b.z) | ((unsigned)f2bf(b.w) << 16);
    ((uint4*)dst)[i] = u;
  }
}

// ---------------- GEMM: C[M,N] = A[M,K] * B[N,K]^T (NT), bf16 in, fp32 acc ----
__global__ __launch_bounds__(256) void gemm_bt(const u16* __restrict__ A,
    const u16* __restrict__ B, void* __restrict__ C,
    int M, int N, int K, int out_mode, const int* __restrict__ flag)
{
  __shared__ u16 As[128*64];
  __shared__ u16 Bs[128*64];
  const int tid  = threadIdx.x;
  const int wave = tid >> 6;
  const int lane = tid & 63;
  const int quad = lane >> 4;
  const int l16  = lane & 15;
  const int wr = wave >> 1, wc = wave & 1;
  const int bm = blockIdx.y * 128;
  const int bn = blockIdx.x * 128;
  const int rsub = lane >> 3;
  const int csub = lane & 7;

  floatx4 acc[4][4];
  #pragma unroll
  for (int i = 0; i < 4; i++)
    #pragma unroll
    for (int j = 0; j < 4; j++)
      #pragma unroll
      for (int r = 0; r < 4; r++) acc[i][j][r] = 0.0f;

  for (int k0 = 0; k0 < K; k0 += 64) {
    #pragma unroll
    for (int i = 0; i < 4; i++) {
      const int s = wave*4 + i;
      const int r = s*8 + rsub;
      const int c = csub ^ (r & 7);
      const size_t goff = (size_t)r * K + (size_t)(k0 + c*8);
      async16(A + (size_t)bm * K + goff, &As[s*512]);
      async16(B + (size_t)bn * K + goff, &Bs[s*512]);
    }
    __syncthreads();
    #pragma unroll
    for (int ks = 0; ks < 2; ks++) {
      short8 fa[4], fb[4];
      #pragma unroll
      for (int mi = 0; mi < 4; mi++) {
        int m = wr*64 + mi*16 + l16;
        int phys = (ks*4 + quad) ^ (m & 7);
        fa[mi] = *(const short8*)&As[m*64 + phys*8];
      }
      #pragma unroll
      for (int ni = 0; ni < 4; ni++) {
        int n = wc*64 + ni*16 + l16;
        int phys = (ks*4 + quad) ^ (n & 7);
        fb[ni] = *(const short8*)&Bs[n*64 + phys*8];
      }
      #pragma unroll
      for (int mi = 0; mi < 4; mi++)
        #pragma unroll
        for (int ni = 0; ni < 4; ni++)
          acc[mi][ni] = __builtin_amdgcn_mfma_f32_16x16x32_bf16(fa[mi], fb[ni], acc[mi][ni], 0, 0, 0);
    }
    __syncthreads();
  }

  const bool outbf = (out_mode == 0) || (*flag != 0);
  #pragma unroll
  for (int mi = 0; mi < 4; mi++) {
    #pragma unroll
    for (int ni = 0; ni < 4; ni++) {
      #pragma unroll
      for (int r = 0; r < 4; r++) {
        int row = bm + wr*64 + mi*16 + quad*4 + r;
        int col = bn + wc*64 + ni*16 + l16;
        float v = acc[mi][ni][r];
        size_t idx = (size_t)row * N + col;
        if (outbf) ((u16*)C)[idx] = f2bf(v);
        else       ((float*)C)[idx] = v;
      }
    }
  }
}

// ---------------- RoPE in place; Q additionally scaled by 1/sqrt(HD) --------
__global__ void rope_kernel(u16* __restrict__ Q, u16* __restrict__ Kb,
                            const int* __restrict__ pos)
{
  int n = blockIdx.x * blockDim.x + threadIdx.x;  // S*NH*64
  if (n >= S_LEN * NH * 64) return;
  int s   = n >> 11;
  int rem = n & 2047;
  int h = rem >> 6;
  int j = rem & 63;
  float p = (float)pos[s];
  float inv = expf(-(float)j * 0.14391156831212787f);  // ln(10000)/64
  float arg = p * inv;
  float c = cosf(arg), sn = sinf(arg);
  const float SC = 0.08838834764831845f;  // 1/sqrt(128), folded into Q
  size_t base = (size_t)s * HID + (size_t)h * HD + j;
  float q1 = bf2f(Q[base]), q2 = bf2f(Q[base + 64]);
  Q[base]      = f2bf((q1 * c - q2 * sn) * SC);
  Q[base + 64] = f2bf((q2 * c + q1 * sn) * SC);
  float k1 = bf2f(Kb[base]), k2 = bf2f(Kb[base + 64]);
  Kb[base]      = f2bf(k1 * c - k2 * sn);
  Kb[base + 64] = f2bf(k2 * c + k1 * sn);
}

// ---------------- attention: one block per (head, 16-row q-tile) ------------
// 1024 threads (16 waves).  NO persistent per-thread score arrays: phase 1
// writes okey(score) u32 straight to LDS kbuf[16][2048] (128 KB).  This is
// the structural fix for the scratch-spill that dominated R1-R3 (hipcc pins
// VGPR=64 for 1024-thread blocks and spills register score arrays to HBM:
// 1-3 GB of WRITE_SIZE).  Peak live set here is ~50 VGPRs -> no spill even
// at 64 VGPRs.
// After one __syncthreads, wave w owns row w end-to-end: private radix
// select over kbuf (4x8-bit passes, exact index tie-break in ascending-j
// order), ballot compaction, softmax, PV gather, O write.  No further
// barriers, no cross-wave atomics; per-row hist is recycled as the weight
// buffer after selection.
// LDS (155,648 B): kbuf u32[16][2048] | hist u32[16][256] (-> weights f32) |
//                  idx u16[16][256]
// Requires dynamic-LDS opt-in >64KB (hipFuncSetAttribute in kernel_launch).
#define ATTN_LDS (131072 + 16384 + 8192)
__global__ __launch_bounds__(1024, 4) void attn_kernel(const u16* __restrict__ Q,
    const u16* __restrict__ Kb, const u16* __restrict__ V, u16* __restrict__ O)
{
  extern __shared__ char smem[];
  unsigned* kbuf = (unsigned*)smem;                   // [16][2048]
  unsigned* hist = (unsigned*)(smem + 131072);        // [16][256], reused
  u16*      idxl = (u16*)(smem + 131072 + 16384);     // [16][256]

  const int tid  = threadIdx.x;
  const int wave = tid >> 6, lane = tid & 63;
  const int quad = lane >> 4, l16 = lane & 15;
  const int quad4 = quad * 4;
  const int qt   = (S_LEN/16 - 1) - blockIdx.x;   // heavy tiles first
  const int q0   = qt * 16;
  const int h    = blockIdx.y;
  const size_t hoff = (size_t)h * HD;
  const int ntile = qt + 1;

  // ---- Phase 1: scores via MFMA, okey -> kbuf.  Wave w does tiles w+16m. --
  {
    short8 afr[4];
    const u16* qrow = Q + (size_t)(q0 + l16) * HID + hoff;
    #pragma unroll
    for (int ks = 0; ks < 4; ks++)
      afr[ks] = *(const short8*)(qrow + ks*32 + quad*8);

    #pragma unroll 1
    for (int jt = wave; jt < ntile; jt += 16) {
      const u16* krow = Kb + (size_t)(jt*16 + l16) * HID + hoff;
      floatx4 acc = {0.f, 0.f, 0.f, 0.f};
      #pragma unroll
      for (int ks = 0; ks < 4; ks++) {
        short8 bfr = *(const short8*)(krow + ks*32 + quad*8);
        acc = __builtin_amdgcn_mfma_f32_16x16x32_bf16(afr[ks], bfr, acc, 0, 0, 0);
      }
      // C layout: row = quad*4 + r, col = jt*16 + l16
      #pragma unroll
      for (int r = 0; r < 4; r++)
        kbuf[((quad4 + r) << 11) + jt*16 + l16] = okey(acc[r]);
    }
  }
  __syncthreads();

  // ---- From here: wave `row` owns query row q0+row exclusively. ----
  const int row = wave;
  const int nv  = q0 + row + 1;            // valid cols are [0, nv)
  unsigned* mykb   = kbuf + (row << 11);
  unsigned* myhist = hist + (row << 8);
  float*    mywgt  = (float*)myhist;       // reuse hist slice after radix
  u16*      myidx  = idxl + (row << 8);

  unsigned pref = 0, rneed = KSEL;
  int shfin = -1;                          // >=0: done at that shift
  const bool need_sel = (nv > KSEL);

  if (need_sel) {
    for (int p = 0; p < 4; p++) {
      const int sh = 24 - 8*p;
      #pragma unroll
      for (int b = 0; b < 4; b++) myhist[(lane << 2) + b] = 0u;
      __asm__ volatile("s_waitcnt lgkmcnt(0)" ::: "memory");
      for (int j0 = 0; j0 < nv; j0 += 64) {
        int j = j0 + lane;
        if (j < nv) {
          unsigned key = mykb[j];
          bool mm = (p == 0) || ((key >> (sh + 8)) == pref);
          if (mm) atomicAdd(&myhist[(key >> sh) & 255u], 1u);
        }
      }
      __asm__ volatile("s_waitcnt lgkmcnt(0)" ::: "memory");
      // wave-level digit scan: 4 bins/lane, descending bin order
      unsigned hv[4], part = 0u;
      const int baseb = 252 - (lane << 2);
      #pragma unroll
      for (int k2 = 0; k2 < 4; k2++) { hv[k2] = myhist[baseb + k2]; part += hv[k2]; }
      unsigned pre = part;
      #pragma unroll
      for (int o = 1; o < 64; o <<= 1) { unsigned v2 = __shfl_up(pre, o, 64); if (lane >= o) pre += v2; }
      pre -= part;                         // keys in strictly higher chunks
      unsigned dig = 0, newr = 0; int donef = 0, found = 0;
      if (pre < rneed && pre + part >= rneed) {     // unique finder lane
        unsigned a = pre;
        #pragma unroll
        for (int k2 = 3; k2 >= 0; k2--) {
          unsigned cc = hv[k2];
          if (a + cc >= rneed) {
            dig = (unsigned)(baseb + k2);
            newr = rneed - a;
            donef = (cc == newr) ? 1 : 0;
            found = 1;
            break;
          }
          a += cc;
        }
      }
      u64 bal = __ballot(found != 0);
      int fl = (int)(__ffsll((long long)bal) - 1);
      dig   = __shfl(dig,   fl, 64);
      newr  = __shfl(newr,  fl, 64);
      donef = __shfl(donef, fl, 64);
      pref  = (pref << 8) | dig;
      rneed = newr;
      if (donef) { shfin = sh; break; }
    }
  }

  // ---- compaction: ballot-scan in ascending j (exact tie-break order) ----
  unsigned cnt = 0, eqbase = 0, maxk = 0;
  for (int j0 = 0; j0 < nv; j0 += 64) {
    int j = j0 + lane;
    unsigned key = 0; bool keep = false;
    if (j < nv) {
      key = mykb[j];
      if (!need_sel)       keep = true;
      else if (shfin >= 0) keep = (key >> shfin) >= pref;
      else                 keep = key > pref;
    }
    if (need_sel && shfin < 0) {
      bool eq = (j < nv) && (key == pref);
      u64 ebal = __ballot(eq);
      if (eq) {
        unsigned erank = (unsigned)__popcll(ebal & ((1ull << lane) - 1ull));
        if (eqbase + erank < rneed) keep = true;
      }
      eqbase += (unsigned)__popcll(ebal);
    }
    u64 kb2 = __ballot(keep);
    if (keep) {
      unsigned pos = cnt + (unsigned)__popcll(kb2 & ((1ull << lane) - 1ull));
      myidx[pos] = (u16)j;
      mywgt[pos] = unokey(key);            // exact f32 score
      maxk = maxk > key ? maxk : key;
    }
    cnt += (unsigned)__popcll(kb2);
  }
  #pragma unroll
  for (int o = 32; o; o >>= 1) { unsigned ot = __shfl_xor(maxk, o, 64); maxk = maxk > ot ? maxk : ot; }
  const int n = (int)cnt;                  // = min(nv, KSEL)
  const float mrow = unokey(maxk);

  // ---- softmax weights ----
  float lsum = 0.f;
  for (int i = lane; i < n; i += 64) {
    float w = __expf(mywgt[i] - mrow);
    mywgt[i] = w;
    lsum += w;
  }
  #pragma unroll
  for (int o = 32; o; o >>= 1) lsum += __shfl_xor(lsum, o, 64);
  const float invs = 1.f / lsum;

  // ---- PV gather: 2 dims/lane, unroll 4 ----
  {
    const int d0 = lane * 2;
    const u16* Vh = V + hoff + d0;
    float a0 = 0.f, a1 = 0.f;
    int i = 0;
    for (; i + 4 <= n; i += 4) {
      int   j0 = myidx[i+0], j1 = myidx[i+1], j2 = myidx[i+2], j3 = myidx[i+3];
      float w0 = mywgt[i+0], w1 = mywgt[i+1], w2 = mywgt[i+2], w3 = mywgt[i+3];
      unsigned p0 = *(const unsigned*)(Vh + (size_t)j0 * HID);
      unsigned p1 = *(const unsigned*)(Vh + (size_t)j1 * HID);
      unsigned p2 = *(const unsigned*)(Vh + (size_t)j2 * HID);
      unsigned p3 = *(const unsigned*)(Vh + (size_t)j3 * HID);
      a0 += w0*__uint_as_float(p0<<16) + w1*__uint_as_float(p1<<16)
          + w2*__uint_as_float(p2<<16) + w3*__uint_as_float(p3<<16);
      a1 += w0*__uint_as_float(p0&0xffff0000u) + w1*__uint_as_float(p1&0xffff0000u)
          + w2*__uint_as_float(p2&0xffff0000u) + w3*__uint_as_float(p3&0xffff0000u);
    }
    for (; i < n; i++) {
      int j = myidx[i]; float w = mywgt[i];
      unsigned p = *(const unsigned*)(Vh + (size_t)j * HID);
      a0 += w*__uint_as_float(p<<16);
      a1 += w*__uint_as_float(p&0xffff0000u);
    }
    unsigned ov = (unsigned)f2bf(a0*invs) | ((unsigned)f2bf(a1*invs) << 16);
    *(unsigned*)(O + (size_t)(q0 + row) * HID + hoff + d0) = ov;
  }
}

// ---------------- launch ----------------
extern "C" void kernel_launch(void* const* d_in, const int* in_sizes, int n_in,
                              void* d_out, int out_size, void* d_ws, size_t ws_size,
                              hipStream_t stream)
{
  (void)in_sizes; (void)n_in; (void)out_size;
  const void* hidden = d_in[0];
  const int*  pos    = (const int*)d_in[2];
  const void* Wq     = d_in[3];
  const void* Wk     = d_in[4];
  const void* Wv     = d_in[5];
  const void* Wo     = d_in[6];

  const size_t SH2 = (size_t)S_LEN * HID * 2;
  const size_t W2  = (size_t)HID * HID * 2;
  const size_t NEEDED = 256 + SH2 + W2 + 3 * SH2 + SH2;
  if (ws_size < NEEDED) {
    sentinel_kernel<<<1, 1, 0, stream>>>((float*)d_out);
    return;
  }

  // opt-in to >64KB dynamic LDS for attn_kernel (one-time, host-side; not a
  // stream op so safe under graph capture)
  static int lds_attr_set = 0;
  if (!lds_attr_set) {
    hipFuncSetAttribute((const void*)attn_kernel,
                        hipFuncAttributeMaxDynamicSharedMemorySize, ATTN_LDS);
    lds_attr_set = 1;
  }

  char* ws = (char*)d_ws;
  int* flag = (int*)ws;
  u16* hb = (u16*)(ws + 256);
  u16* wb = (u16*)(ws + 256 + SH2);
  u16* qb = (u16*)(ws + 256 + SH2 + W2);
  u16* kb = (u16*)(ws + 256 + SH2 + W2 + SH2);
  u16* vb = (u16*)(ws + 256 + SH2 + W2 + 2 * SH2);
  u16* ab = (u16*)(ws + 256 + SH2 + W2 + 3 * SH2);

  detect_dtype<<<1, 64, 0, stream>>>((const u16*)hidden, flag);

  const int nh8 = S_LEN * HID / 8;
  const int nw8 = HID * HID / 8;
  to_bf16<<<nh8 / 256, 256, 0, stream>>>(hidden, hb, nh8, flag);

  dim3 ggrid(HID / 128, S_LEN / 128);

  to_bf16<<<nw8 / 256, 256, 0, stream>>>(Wq, wb, nw8, flag);
  gemm_bt<<<ggrid, 256, 0, stream>>>(hb, wb, (void*)qb, S_LEN, HID, HID, 0, flag);

  to_bf16<<<nw8 / 256, 256, 0, stream>>>(Wk, wb, nw8, flag);
  gemm_bt<<<ggrid, 256, 0, stream>>>(hb, wb, (void*)kb, S_LEN, HID, HID, 0, flag);

  to_bf16<<<nw8 / 256, 256, 0, stream>>>(Wv, wb, nw8, flag);
  gemm_bt<<<ggrid, 256, 0, stream>>>(hb, wb, (void*)vb, S_LEN, HID, HID, 0, flag);

  rope_kernel<<<(S_LEN * NH * 64) / 256, 256, 0, stream>>>(qb, kb, pos);

  attn_kernel<<<dim3(S_LEN / 16, NH), 1024, ATTN_LDS, stream>>>(qb, kb, vb, ab);

  to_bf16<<<nw8 / 256, 256, 0, stream>>>(Wo, wb, nw8, flag);
  gemm_bt<<<ggrid, 256, 0, stream>>>(ab, wb, d_out, S_LEN, HID, HID, 1, flag);
}